// Round 11
// baseline (145.176 us; speedup 1.0000x reference)
//
#include <hip/hip_runtime.h>
#include <hip/hip_bf16.h>

typedef unsigned short u16;
typedef __attribute__((ext_vector_type(8))) short short8;
typedef __attribute__((ext_vector_type(4))) float float4v;
typedef __attribute__((ext_vector_type(4))) unsigned int uint4v;

#define BATCH 8
#define SLEN  200
#define NNODE 512
#define NEDGE 2048
#define NEGV  -9000000000000000.0f

#define H1S 40    // h1p row stride in bf16 (80 B; 20-dword bank shift/row)
#define H1R 212   // 2 pad + 200 data + 10 pad

__device__ __forceinline__ u16 f2bf(float f) {
    unsigned int x = __float_as_uint(f);
    unsigned int lsb = (x >> 16) & 1u;
    x += 0x7fffu + lsb;
    return (u16)(x >> 16);
}

__device__ __forceinline__ float bf2f(u16 u) {
    return __uint_as_float(((unsigned int)u) << 16);
}

__device__ __forceinline__ unsigned int pk2(float a, float b) {
    __hip_bfloat162 h = __float22bfloat162_rn(make_float2(a, b));
    unsigned int r;
    __builtin_memcpy(&r, &h, 4);
    return r;
}

// ---------------------------------------------------------------------------
// conv_fused_kernel: 2 nodes/block, double-buffered h1p, grid 2048 x 256.
// conv1 via MFMA (R10, bit-exact validated). Round 11: pre_kernel ELIMINATED
// (5->4 launches). conv2 B-frags self-packed from w2 in TWO sequential
// 40-float scopes with a sched_barrier between them — avoids R6's 80-live
// spill (R6: VGPR 76 + doubled FETCH = spill; cost +23 us). Per-block cost
// now ~20 L2-broadcast float4 loads + 80 pk2 ~ 0.1 us.
// ---------------------------------------------------------------------------
__global__ __launch_bounds__(256) void conv_fused_kernel(
    const float* __restrict__ x,    // (8, 200, 1024)
    const float* __restrict__ w1,   // (32, 2, 5)
    const float* __restrict__ b1,   // (32,)
    const float* __restrict__ b2,   // (64,)
    const float* __restrict__ W1,   // (64, 64)
    const float* __restrict__ a1,   // (128, 1)
    const float* __restrict__ w2,   // (64, 32, 5) conv2 raw weights
    u16* __restrict__ Wh_bt,        // (8, 64, 512) bf16 [b][o][node]
    float* __restrict__ f1,         // (4096,)
    float* __restrict__ f2)         // (4096,)
{
    __shared__ __align__(16) u16 h1pA[H1R * H1S];   // node-0 buffer
    __shared__ __align__(16) u16 h1pB[H1R * H1S];   // node-1 buffer
    __shared__ __align__(16) unsigned int xi[2][224]; // interleaved bf16 x (+pad)
    __shared__ float red[4][2][32];
    __shared__ float hm[2][64];
    __shared__ float part[2][4][64];

    const int t    = threadIdx.x;
    const int blk  = blockIdx.x;
    const int b    = blk >> 8;
    const int pair = blk & 255;
    const int n0   = pair * 2;
    const int lane = t & 63;
    const int wv   = t >> 6;
    const int ml   = lane & 15;
    const int q    = lane >> 4;
    const int o2 = wv & 1;
    const int mh = wv >> 1;

    // conv2 B-frags, self-packed from w2 (bit-identical to old pre_kernel):
    // wfA[kk] word d = pk2(A0[d*5+kk], A1[d*5+kk]) with A0/A1 the two
    // contiguous 20-float runs (ic = 4q..4q+3 and 16+4q..16+4q+3) of oc.
    // Two sequential scopes + sched_barrier keep peak live ~40 floats.
    short8 wfA[5], wfB[5];
    {
        const float* pA0 = w2 + (size_t)(o2 * 32 + ml) * 160 + 20 * q;
        const float* pA1 = pA0 + 80;
        {
            float A0[20], A1[20];
            #pragma unroll
            for (int c = 0; c < 5; ++c) {
                *(float4*)&A0[4 * c] = *(const float4*)(pA0 + 4 * c);
                *(float4*)&A1[4 * c] = *(const float4*)(pA1 + 4 * c);
            }
            #pragma unroll
            for (int kk = 0; kk < 5; ++kk) {
                unsigned int wa[4];
                #pragma unroll
                for (int d = 0; d < 4; ++d)
                    wa[d] = pk2(A0[d * 5 + kk], A1[d * 5 + kk]);
                __builtin_memcpy(&wfA[kk], wa, 16);
            }
        }
        __builtin_amdgcn_sched_barrier(0);   // do NOT hoist B loads over A pack
        {
            const float* pB0 = pA0 + 16 * 160;
            const float* pB1 = pB0 + 80;
            float B0[20], B1[20];
            #pragma unroll
            for (int c = 0; c < 5; ++c) {
                *(float4*)&B0[4 * c] = *(const float4*)(pB0 + 4 * c);
                *(float4*)&B1[4 * c] = *(const float4*)(pB1 + 4 * c);
            }
            #pragma unroll
            for (int kk = 0; kk < 5; ++kk) {
                unsigned int wb[4];
                #pragma unroll
                for (int d = 0; d < 4; ++d)
                    wb[d] = pk2(B0[d * 5 + kk], B1[d * 5 + kk]);
                __builtin_memcpy(&wfB[kk], wb, 16);
            }
        }
        __builtin_amdgcn_sched_barrier(0);
    }
    const float bias2a = b2[o2 * 32 + ml];
    const float bias2b = b2[o2 * 32 + 16 + ml];

    // conv1 B-frags: B[k][oc] = k<10 ? w1[oc][ch=k&1][tap=k>>1] : 0
    short8 w1f0, w1f1;
    {
        u16 v0[8], v1[8];
        #pragma unroll
        for (int j = 0; j < 8; ++j) {
            const int k = q * 8 + j;
            const int widx = (k & 1) * 5 + (k >> 1);
            v0[j] = (k < 10) ? f2bf(w1[ml * 10 + widx])        : (u16)0;
            v1[j] = (k < 10) ? f2bf(w1[(16 + ml) * 10 + widx]) : (u16)0;
        }
        __builtin_memcpy(&w1f0, v0, 16);
        __builtin_memcpy(&w1f1, v1, 16);
    }
    const float b1lo = b1[ml];
    const float b1hi = b1[16 + ml];

    // stage x for BOTH nodes, channel-interleaved bf16: xi[nd][s] packs
    // (x0[s-2], x1[s-2]); slots 0,1 and 202..223 are zero pads.
    if (t < SLEN) {
        const float4 xv = *(const float4*)(x + ((size_t)(b * SLEN + t)) * 1024 + 4 * pair);
        xi[0][2 + t] = pk2(xv.x, xv.y);
        xi[1][2 + t] = pk2(xv.z, xv.w);
    } else if (t < 224) {
        const int pp = (t < 202) ? (t - 200) : t;
        xi[0][pp] = 0u;
        xi[1][pp] = 0u;
    }
    {
        unsigned int* hzA = (unsigned int*)h1pA;
        unsigned int* hzB = (unsigned int*)h1pB;
        if (t < 40)       { hzA[t] = 0u;        hzB[t] = 0u; }
        else if (t < 240) { hzA[4000 + t] = 0u; hzB[4000 + t] = 0u; }  // rows 202..211
    }
    __syncthreads();

// conv1 via MFMA: wave wv owns m-tiles {wv, wv+4, wv+8} (+12 for wv==0).
// A-frag row = ml, k-slice = 4 contiguous u32 of xi. C layout: col=lane&15,
// row = q*4+r. mt==12 guard q<2 keeps m<200 (pad rows stay zero).
#define CONV1_NODE(nd, H1P) do {                                              \
    const int nTi = (wv == 0) ? 4 : 3;                                        \
    for (int ti = 0; ti < nTi; ++ti) {                                        \
        const int mt = wv + 4 * ti;                                           \
        unsigned int aw[4];                                                   \
        const int bi = mt * 16 + ml + 4 * q;                                  \
        aw[0] = xi[nd][bi];     aw[1] = xi[nd][bi + 1];                       \
        aw[2] = xi[nd][bi + 2]; aw[3] = xi[nd][bi + 3];                       \
        short8 af; __builtin_memcpy(&af, aw, 16);                             \
        float4v c0 = {0.f, 0.f, 0.f, 0.f};                                    \
        float4v c1 = {0.f, 0.f, 0.f, 0.f};                                    \
        c0 = __builtin_amdgcn_mfma_f32_16x16x32_bf16(af, w1f0, c0, 0, 0, 0);  \
        c1 = __builtin_amdgcn_mfma_f32_16x16x32_bf16(af, w1f1, c1, 0, 0, 0);  \
        if (mt < 12 || q < 2) {                                               \
            _Pragma("unroll")                                                 \
            for (int r = 0; r < 4; ++r) {                                     \
                const int m = mt * 16 + q * 4 + r;                            \
                *(unsigned int*)&H1P[(2 + m) * H1S + 2 * ml] =                \
                    pk2(fmaxf(c0[r] + b1lo, 0.f), fmaxf(c1[r] + b1hi, 0.f));  \
            }                                                                 \
        }                                                                     \
    }                                                                         \
} while (0)

#define CONV2_NODE(nd, H1P) do {                                              \
    float tA = 0.f, tB = 0.f;                                                 \
    const int mt0 = mh * 7, mtE = mh ? 13 : 7;                                \
    for (int mt = mt0; mt < mtE; ++mt) {                                      \
        float4v acc0 = {0.f, 0.f, 0.f, 0.f};                                  \
        float4v acc1 = {0.f, 0.f, 0.f, 0.f};                                  \
        _Pragma("unroll")                                                     \
        for (int kk = 0; kk < 5; ++kk) {                                      \
            const short8 a = *(const short8*)&H1P[(mt * 16 + ml + kk) * H1S + q * 8]; \
            acc0 = __builtin_amdgcn_mfma_f32_16x16x32_bf16(a, wfA[kk], acc0, 0, 0, 0); \
            acc1 = __builtin_amdgcn_mfma_f32_16x16x32_bf16(a, wfB[kk], acc1, 0, 0, 0); \
        }                                                                     \
        if (mt < 12) {                                                        \
            _Pragma("unroll")                                                 \
            for (int r = 0; r < 4; ++r) {                                     \
                tA += fmaxf(acc0[r] + bias2a, 0.f);                           \
                tB += fmaxf(acc1[r] + bias2b, 0.f);                           \
            }                                                                 \
        } else if (q < 2) {   /* m = 192 + q*4 + r < 200 */                   \
            _Pragma("unroll")                                                 \
            for (int r = 0; r < 4; ++r) {                                     \
                tA += fmaxf(acc0[r] + bias2a, 0.f);                           \
                tB += fmaxf(acc1[r] + bias2b, 0.f);                           \
            }                                                                 \
        }                                                                     \
    }                                                                         \
    tA += __shfl_xor(tA, 16, 64);                                             \
    tA += __shfl_xor(tA, 32, 64);                                             \
    tB += __shfl_xor(tB, 16, 64);                                             \
    tB += __shfl_xor(tB, 32, 64);                                             \
    tAn[nd] = tA;                                                             \
    tBn[nd] = tB;                                                             \
} while (0)

    float tAn[2], tBn[2];

    // conv1 node0 -> h1pA
    CONV1_NODE(0, h1pA);
    __syncthreads();

    // conv2(n0) from h1pA ; conv1(n1) into h1pB — independent buffers
    CONV2_NODE(0, h1pA);
    CONV1_NODE(1, h1pB);
    __syncthreads();

    // conv2 node1 from h1pB
    CONV2_NODE(1, h1pB);

#undef CONV1_NODE
#undef CONV2_NODE

    if (lane < 16) {
        red[wv][0][ml]      = tAn[0];   // oc = o2*32 + ml
        red[wv][0][16 + ml] = tBn[0];   // oc = o2*32 + 16 + ml
        red[wv][1][ml]      = tAn[1];
        red[wv][1][16 + ml] = tBn[1];
    }
    __syncthreads();
    if (t < 128) {
        const int nd = t >> 6, o = t & 63;
        const int grp = (o >> 5), idx = o & 31;   // waves grp, grp+2 hold this oc
        hm[nd][o] = (red[grp][nd][idx] + red[grp + 2][nd][idx]) * (1.0f / 200.0f);
    }
    __syncthreads();

    // fused Wh1 = hm @ W1 (f32); both nodes share the W1 column loads
    {
        const int o = t & 63, q4 = t >> 6;
        const float* Wp = W1 + (q4 * 16) * 64 + o;
        float p0 = 0.f, p1 = 0.f;
        #pragma unroll
        for (int k = 0; k < 16; ++k) {
            const float w = Wp[k * 64];
            p0 += hm[0][q4 * 16 + k] * w;
            p1 += hm[1][q4 * 16 + k] * w;
        }
        part[0][q4][o] = p0;
        part[1][q4][o] = p1;
    }
    __syncthreads();
    if (t < 128) {
        const int nd = t >> 6, o = t & 63;
        const int n = n0 + nd;
        const float v = part[nd][0][o] + part[nd][1][o] + part[nd][2][o] + part[nd][3][o];
        Wh_bt[((size_t)(b * 64 + o)) * 512 + n] = f2bf(v);
        float v1 = v * a1[o];
        float v2 = v * a1[64 + o];
        #pragma unroll
        for (int off = 32; off; off >>= 1) {
            v1 += __shfl_xor(v1, off, 64);
            v2 += __shfl_xor(v2, off, 64);
        }
        if (o == 0) { f1[b * 512 + n] = v1; f2[b * 512 + n] = v2; }
    }
}

// ---------------------------------------------------------------------------
// gat_attn_kernel: R5 structure (16-row i-tiles, 512 thr, 8 waves, accH
// K-split) + self-mask from adj + self-packed W2 B-frag (R9/R10-validated).
// ---------------------------------------------------------------------------
#define PSTR 520
__global__ __launch_bounds__(512) void gat_attn_kernel(
    const u16* __restrict__ Wh_bt,   // (8, 64, 512) bf16
    const float* __restrict__ f1in,
    const float* __restrict__ f2in,
    const int* __restrict__ adj,     // (512, 512)
    const float* __restrict__ W2g,   // (64, 64) GAT layer-2 W (fuse=1)
    const float* __restrict__ a2,    // (128,)       (fuse=1)
    u16* __restrict__ whbt_out,      // (8, 64, 512) (fuse=1)
    float* __restrict__ f1out,       //              (fuse=1)
    float* __restrict__ f2out,       //              (fuse=1)
    u16* __restrict__ outp,          // (4096, 64) bf16 (fuse=0)
    const int fuse)
{
    __shared__ __align__(16) u16 P[16 * PSTR];
    __shared__ float f2s[512];
    __shared__ float invs[16];
    __shared__ float f1s[16];
    __shared__ float accH[4][64][4];
    __shared__ __align__(16) u16 g1s[16 * 72];
    __shared__ __align__(16) u16 wh2s[64 * 20];
    __shared__ float fp1[4][16], fp2[4][16];

    const int t   = threadIdx.x;
    const int blk = blockIdx.x;
    const int b   = blk >> 5;
    const int i0  = (blk & 31) * 16;
    const int lane = t & 63, wv = t >> 6, nt = wv & 3, kh = wv >> 2;
    const int ml = lane & 15, q = lane >> 4;

    // prefetch B fragments for phase 2 (issue before softmax work)
    const u16* Bp = Wh_bt + ((size_t)(b * 64 + nt * 16 + ml)) * 512 + kh * 256 + q * 8;
    short8 bfr[8];
    #pragma unroll
    for (int ks = 0; ks < 8; ++ks)
        bfr[ks] = *(const short8*)(Bp + ks * 32);

    // adj row segment for phase-1 mask
    const int i_row = t >> 5, jseg0 = t & 31;
    const int4* ap = (const int4*)(adj + (size_t)(i0 + i_row) * 512 + jseg0 * 16);
    const int4 m0 = ap[0], m1 = ap[1], m2 = ap[2], m3 = ap[3];

    // W2 column floats for the fuse epilogue B-frag (packed later)
    float wgv[8];
    if (fuse) {
        #pragma unroll
        for (int j = 0; j < 8; ++j)
            wgv[j] = W2g[(kh * 32 + q * 8 + j) * 64 + nt * 16 + ml];
    }

    f2s[t & 511] = f2in[b * 512 + (t & 511)];
    if (t < 16) f1s[t] = f1in[b * 512 + i0 + t];
    __syncthreads();

    // phase 1: thread = (i_row, jseg0) -> 16 j's via in-register adj bits
    {
        const float f1i = f1s[i_row];
        unsigned int mbits = 0;
        mbits |= (m0.x > 0) ? 0x0001u : 0u;  mbits |= (m0.y > 0) ? 0x0002u : 0u;
        mbits |= (m0.z > 0) ? 0x0004u : 0u;  mbits |= (m0.w > 0) ? 0x0008u : 0u;
        mbits |= (m1.x > 0) ? 0x0010u : 0u;  mbits |= (m1.y > 0) ? 0x0020u : 0u;
        mbits |= (m1.z > 0) ? 0x0040u : 0u;  mbits |= (m1.w > 0) ? 0x0080u : 0u;
        mbits |= (m2.x > 0) ? 0x0100u : 0u;  mbits |= (m2.y > 0) ? 0x0200u : 0u;
        mbits |= (m2.z > 0) ? 0x0400u : 0u;  mbits |= (m2.w > 0) ? 0x0800u : 0u;
        mbits |= (m3.x > 0) ? 0x1000u : 0u;  mbits |= (m3.y > 0) ? 0x2000u : 0u;
        mbits |= (m3.z > 0) ? 0x4000u : 0u;  mbits |= (m3.w > 0) ? 0x8000u : 0u;
        const float* f2p = f2s + jseg0 * 16;
        float ev[16];
        float mx = -3.0e38f;
        #pragma unroll
        for (int v = 0; v < 16; ++v) {
            float e = f1i + f2p[v];
            e = e > 0.f ? e : 0.2f * e;
            e = ((mbits >> v) & 1u) ? e : NEGV;
            ev[v] = e;
            mx = fmaxf(mx, e);
        }
        mx = fmaxf(mx, __shfl_xor(mx, 1, 64));
        mx = fmaxf(mx, __shfl_xor(mx, 2, 64));
        mx = fmaxf(mx, __shfl_xor(mx, 4, 64));
        mx = fmaxf(mx, __shfl_xor(mx, 8, 64));
        mx = fmaxf(mx, __shfl_xor(mx, 16, 64));
        float sum = 0.f;
        #pragma unroll
        for (int v = 0; v < 16; ++v) {
            const float ex = __expf(ev[v] - mx);
            ev[v] = ex;
            sum += ex;
        }
        sum += __shfl_xor(sum, 1, 64);
        sum += __shfl_xor(sum, 2, 64);
        sum += __shfl_xor(sum, 4, 64);
        sum += __shfl_xor(sum, 8, 64);
        sum += __shfl_xor(sum, 16, 64);
        if (jseg0 == 0) invs[i_row] = 1.0f / sum;
        unsigned int* prow = (unsigned int*)&P[i_row * PSTR + jseg0 * 16];
        #pragma unroll
        for (int v = 0; v < 8; ++v)
            prow[v] = pk2(ev[2 * v], ev[2 * v + 1]);
    }
    __syncthreads();

    // phase 2: out(16x64) = P(16x512) @ Wh(512x64); wave = (nt, kh)
    float4v acc = {0.f, 0.f, 0.f, 0.f};
    #pragma unroll
    for (int ks = 0; ks < 8; ++ks) {
        const short8 afr = *(const short8*)&P[ml * PSTR + kh * 256 + ks * 32 + q * 8];
        acc = __builtin_amdgcn_mfma_f32_16x16x32_bf16(afr, bfr[ks], acc, 0, 0, 0);
    }
    if (kh == 1) {
        #pragma unroll
        for (int r = 0; r < 4; ++r) accH[nt][lane][r] = acc[r];
    }
    __syncthreads();
    if (kh == 0) {
        #pragma unroll
        for (int r = 0; r < 4; ++r) {
            const int i2 = q * 4 + r;
            float val = (acc[r] + accH[nt][lane][r]) * invs[i2];
            if (fuse) {
                val = fmaxf(val, 0.f);
                g1s[i2 * 72 + nt * 16 + ml] = f2bf(val);
            } else {
                outp[((size_t)(b * 512 + i0 + i2)) * 64 + nt * 16 + ml] = f2bf(val);
            }
        }
    }

    if (!fuse) return;

    // fused layer-2 Wh: Wh2(16x64) = g1s @ W2 ; wave = (nt, kh), 1 MFMA each
    __syncthreads();
    const short8 af2 = *(const short8*)&g1s[ml * 72 + kh * 32 + q * 8];
    short8 bf2v;
    {
        unsigned int wgp[4];
        #pragma unroll
        for (int d = 0; d < 4; ++d)
            wgp[d] = pk2(wgv[2 * d], wgv[2 * d + 1]);
        __builtin_memcpy(&bf2v, wgp, 16);
    }
    float4v c2 = {0.f, 0.f, 0.f, 0.f};
    c2 = __builtin_amdgcn_mfma_f32_16x16x32_bf16(af2, bf2v, c2, 0, 0, 0);
    if (kh == 1) {
        #pragma unroll
        for (int r = 0; r < 4; ++r) accH[nt][lane][r] = c2[r];
    }
    __syncthreads();
    if (kh == 0) {
        const int o = nt * 16 + ml;
        const float a2o1 = a2[o], a2o2 = a2[64 + o];
        #pragma unroll
        for (int r = 0; r < 4; ++r) {
            const float wv2 = c2[r] + accH[nt][lane][r];
            wh2s[o * 20 + q * 4 + r] = f2bf(wv2);
            float p1 = wv2 * a2o1, p2 = wv2 * a2o2;
            p1 += __shfl_xor(p1, 1, 64); p2 += __shfl_xor(p2, 1, 64);
            p1 += __shfl_xor(p1, 2, 64); p2 += __shfl_xor(p2, 2, 64);
            p1 += __shfl_xor(p1, 4, 64); p2 += __shfl_xor(p2, 4, 64);
            p1 += __shfl_xor(p1, 8, 64); p2 += __shfl_xor(p2, 8, 64);
            if (ml == 0) {
                fp1[nt][q * 4 + r] = p1;
                fp2[nt][q * 4 + r] = p2;
            }
        }
    }
    __syncthreads();
    if (t < 256) {
        const int o = t >> 2, seg = t & 3;
        *(uint2*)&whbt_out[((size_t)(b * 64 + o)) * 512 + i0 + seg * 4] =
            *(const uint2*)&wh2s[o * 20 + seg * 4];
    }
    if (t < 16) {
        f1out[b * 512 + i0 + t] = fp1[0][t] + fp1[1][t] + fp1[2][t] + fp1[3][t];
        f2out[b * 512 + i0 + t] = fp2[0][t] + fp2[1][t] + fp2[2][t] + fp2[3][t];
    }
}

// ---------------------------------------------------------------------------
// Kernel: edge MLP via MFMA, 16 edges/block. fc1 B-frags self-packed from
// fc1w (R9/R10-validated). hg is BF16 (pre-rounded in gat2): uint4 gather.
// ---------------------------------------------------------------------------
#define FSTR 136
__global__ __launch_bounds__(256) void edge_mlp_kernel(
    const u16* __restrict__ hg,         // (4096, 64) bf16
    const int* __restrict__ eidx,       // (2048, 2)
    const float* __restrict__ fc1w,     // (128, 64)
    const float* __restrict__ fc1b,     // (64,)
    const float* __restrict__ fc2w,     // (64, 1)
    const float* __restrict__ fc2b,     // (1,)
    float* __restrict__ out)            // (8, 2048)
{
    __shared__ __align__(16) u16 he[16 * FSTR];
    __shared__ float part[16][4];

    const int t   = threadIdx.x;
    const int blk = blockIdx.x;
    const int b   = blk >> 7;
    const int e0  = (blk & 127) * 16;
    const int lane = t & 63, wv = t >> 6, ml = lane & 15, q = lane >> 4;

    const int o = 16 * wv + ml;
    float fwv[32];
    #pragma unroll
    for (int ks = 0; ks < 4; ++ks) {
        #pragma unroll
        for (int j = 0; j < 8; ++j)
            fwv[ks * 8 + j] = fc1w[(ks * 32 + q * 8 + j) * 64 + o];
    }
    const float bo = fc1b[o];
    const float wo = fc2w[o];

    {
        const int ep = t >> 4, p = t & 15;
        const int e = e0 + ep;
        const int node = (p < 8) ? eidx[e * 2] : eidx[e * 2 + 1];
        const int c0 = (p & 7) * 8;
        const u16* hp = hg + ((size_t)(b * 512 + node)) * 64 + c0;
        *(uint4v*)&he[ep * FSTR + ((p < 8) ? 0 : 64) + c0] = *(const uint4v*)hp;
    }
    __syncthreads();

    short8 bw[4];
    #pragma unroll
    for (int ks = 0; ks < 4; ++ks) {
        unsigned int wp[4];
        #pragma unroll
        for (int d = 0; d < 4; ++d)
            wp[d] = pk2(fwv[ks * 8 + 2 * d], fwv[ks * 8 + 2 * d + 1]);
        __builtin_memcpy(&bw[ks], wp, 16);
    }

    float4v acc = {0.f, 0.f, 0.f, 0.f};
    #pragma unroll
    for (int ks = 0; ks < 4; ++ks) {
        const short8 afr = *(const short8*)&he[ml * FSTR + ks * 32 + q * 8];
        acc = __builtin_amdgcn_mfma_f32_16x16x32_bf16(afr, bw[ks], acc, 0, 0, 0);
    }
    #pragma unroll
    for (int r = 0; r < 4; ++r) {
        float z = fmaxf(acc[r] + bo, 0.f) * wo;
        z += __shfl_xor(z, 1, 64);
        z += __shfl_xor(z, 2, 64);
        z += __shfl_xor(z, 4, 64);
        z += __shfl_xor(z, 8, 64);
        if (ml == 0) part[q * 4 + r][wv] = z;
    }
    __syncthreads();
    if (t < 16) {
        const float v = part[t][0] + part[t][1] + part[t][2] + part[t][3] + fc2b[0];
        out[b * 2048 + e0 + t] = 1.0f / (1.0f + __expf(-v));
    }
}

// ---------------------------------------------------------------------------
extern "C" void kernel_launch(void* const* d_in, const int* in_sizes, int n_in,
                              void* d_out, int out_size, void* d_ws, size_t ws_size,
                              hipStream_t stream) {
    const float* x    = (const float*)d_in[0];
    const int* adj    = (const int*)d_in[1];
    const int* eidx   = (const int*)d_in[2];
    const float* w1   = (const float*)d_in[3];
    const float* b1   = (const float*)d_in[4];
    const float* w2   = (const float*)d_in[5];
    const float* b2   = (const float*)d_in[6];
    const float* W1   = (const float*)d_in[7];
    const float* a1   = (const float*)d_in[8];
    const float* W2   = (const float*)d_in[9];
    const float* a2   = (const float*)d_in[10];
    const float* fc1w = (const float*)d_in[11];
    const float* fc1b = (const float*)d_in[12];
    const float* fc2w = (const float*)d_in[13];
    const float* fc2b = (const float*)d_in[14];
    float* out = (float*)d_out;

    float* ws = (float*)d_ws;
    const size_t R = (size_t)BATCH * NNODE;       // 4096
    float* f1a   = ws;                            // R
    float* f2a   = f1a + R;                       // R
    float* f1b   = f2a + R;                       // R
    float* f2b   = f1b + R;                       // R
    u16*   g_bt  = (u16*)(f2b + R);               // R*64 bf16 (layer-2 out)
    u16*   whbt1 = g_bt + R * 64;                 // R*64
    u16*   whbt2 = whbt1 + R * 64;                // R*64

    conv_fused_kernel<<<dim3(2048), dim3(256), 0, stream>>>(
        x, w1, b1, b2, W1, a1, w2, whbt1, f1a, f2a);
    gat_attn_kernel<<<dim3(256), dim3(512), 0, stream>>>(
        whbt1, f1a, f2a, adj, W2, a2, whbt2, f1b, f2b, g_bt, 1);
    gat_attn_kernel<<<dim3(256), dim3(512), 0, stream>>>(
        whbt2, f1b, f2b, adj, W2, a2, whbt2, f1b, f2b, g_bt, 0);
    edge_mlp_kernel<<<dim3(1024), dim3(256), 0, stream>>>(
        g_bt, eidx, fc1w, fc1b, fc2w, fc2b, out);
}

// Round 12
// 131.197 us; speedup vs baseline: 1.1065x; 1.1065x over previous
//
#include <hip/hip_runtime.h>
#include <hip/hip_bf16.h>

typedef unsigned short u16;
typedef __attribute__((ext_vector_type(8))) short short8;
typedef __attribute__((ext_vector_type(4))) float float4v;
typedef __attribute__((ext_vector_type(4))) unsigned int uint4v;

#define BATCH 8
#define SLEN  200
#define NNODE 512
#define NEDGE 2048
#define NEGV  -9000000000000000.0f

#define H1S 40    // h1p row stride in bf16 (80 B; 20-dword bank shift/row)
#define H1R 212   // 2 pad + 200 data + 10 pad

__device__ __forceinline__ u16 f2bf(float f) {
    unsigned int x = __float_as_uint(f);
    unsigned int lsb = (x >> 16) & 1u;
    x += 0x7fffu + lsb;
    return (u16)(x >> 16);
}

__device__ __forceinline__ float bf2f(u16 u) {
    return __uint_as_float(((unsigned int)u) << 16);
}

__device__ __forceinline__ unsigned int pk2(float a, float b) {
    __hip_bfloat162 h = __float22bfloat162_rn(make_float2(a, b));
    unsigned int r;
    __builtin_memcpy(&r, &h, 4);
    return r;
}

// ---------------------------------------------------------------------------
// pre_kernel — stripped to the w2f pack only (R8/R9 validated). Grid 4.
// R6/R7/R11 lesson (3x falsified): folding this pack into conv always costs
// +14-23 us in conv (spill / per-block redo) vs a hoped ~10 us launch saving
// that never materialized. 5 launches is the floor configuration.
// ---------------------------------------------------------------------------
__global__ __launch_bounds__(256) void pre_kernel(
    const float* __restrict__ w2,    // (64, 32, 5) conv2
    u16* __restrict__ w2f)           // 20*64*8
{
    const int t0 = blockIdx.x * 256 + threadIdx.x;
    for (int idx = t0; idx < 20 * 64 * 8; idx += 1024) {
        const int fid = idx >> 9, rem = idx & 511;
        const int lane = rem >> 3, j = rem & 7;
        const int kk = fid >> 2, ot = fid & 3;
        const int ml = lane & 15, q = lane >> 4;
        const int c  = q * 8 + j;
        const int ic = (c & 1) * 16 + (c >> 1);
        const int oc = ot * 16 + ml;
        w2f[idx] = f2bf(w2[(size_t)oc * 160 + ic * 5 + kk]);
    }
}

// ---------------------------------------------------------------------------
// conv_fused_kernel: 2 nodes/block, double-buffered h1p, grid 2048 x 256.
// conv1 via MFMA (R10, bit-exact validated): channel-interleaved xi makes
// im2col A-frag rows contiguous; B from w1 zero-padded to K=32; output
// written to the same interleaved h1p u32 slots so conv2 is byte-identical.
// ---------------------------------------------------------------------------
__global__ __launch_bounds__(256) void conv_fused_kernel(
    const float* __restrict__ x,    // (8, 200, 1024)
    const float* __restrict__ w1,   // (32, 2, 5)
    const float* __restrict__ b1,   // (32,)
    const float* __restrict__ b2,   // (64,)
    const float* __restrict__ W1,   // (64, 64)
    const float* __restrict__ a1,   // (128, 1)
    const u16* __restrict__ w2f,
    u16* __restrict__ Wh_bt,        // (8, 64, 512) bf16 [b][o][node]
    float* __restrict__ f1,         // (4096,)
    float* __restrict__ f2)         // (4096,)
{
    __shared__ __align__(16) u16 h1pA[H1R * H1S];   // node-0 buffer
    __shared__ __align__(16) u16 h1pB[H1R * H1S];   // node-1 buffer
    __shared__ __align__(16) unsigned int xi[2][224]; // interleaved bf16 x (+pad)
    __shared__ float red[4][2][32];
    __shared__ float hm[2][64];
    __shared__ float part[2][4][64];

    const int t    = threadIdx.x;
    const int blk  = blockIdx.x;
    const int b    = blk >> 8;
    const int pair = blk & 255;
    const int n0   = pair * 2;
    const int lane = t & 63;
    const int wv   = t >> 6;
    const int ml   = lane & 15;
    const int q    = lane >> 4;
    const int o2 = wv & 1;
    const int mh = wv >> 1;

    // conv2 B-frags (prepacked)
    short8 wfA[5], wfB[5];
    #pragma unroll
    for (int kk = 0; kk < 5; ++kk) {
        wfA[kk] = *(const short8*)(w2f + ((kk * 4 + o2 * 2 + 0) * 64 + lane) * 8);
        wfB[kk] = *(const short8*)(w2f + ((kk * 4 + o2 * 2 + 1) * 64 + lane) * 8);
    }
    const float bias2a = b2[o2 * 32 + ml];
    const float bias2b = b2[o2 * 32 + 16 + ml];

    // conv1 B-frags: B[k][oc] = k<10 ? w1[oc][ch=k&1][tap=k>>1] : 0
    short8 w1f0, w1f1;
    {
        u16 v0[8], v1[8];
        #pragma unroll
        for (int j = 0; j < 8; ++j) {
            const int k = q * 8 + j;
            const int widx = (k & 1) * 5 + (k >> 1);
            v0[j] = (k < 10) ? f2bf(w1[ml * 10 + widx])        : (u16)0;
            v1[j] = (k < 10) ? f2bf(w1[(16 + ml) * 10 + widx]) : (u16)0;
        }
        __builtin_memcpy(&w1f0, v0, 16);
        __builtin_memcpy(&w1f1, v1, 16);
    }
    const float b1lo = b1[ml];
    const float b1hi = b1[16 + ml];

    // stage x for BOTH nodes, channel-interleaved bf16: xi[nd][s] packs
    // (x0[s-2], x1[s-2]); slots 0,1 and 202..223 are zero pads.
    if (t < SLEN) {
        const float4 xv = *(const float4*)(x + ((size_t)(b * SLEN + t)) * 1024 + 4 * pair);
        xi[0][2 + t] = pk2(xv.x, xv.y);
        xi[1][2 + t] = pk2(xv.z, xv.w);
    } else if (t < 224) {
        const int pp = (t < 202) ? (t - 200) : t;
        xi[0][pp] = 0u;
        xi[1][pp] = 0u;
    }
    {
        unsigned int* hzA = (unsigned int*)h1pA;
        unsigned int* hzB = (unsigned int*)h1pB;
        if (t < 40)       { hzA[t] = 0u;        hzB[t] = 0u; }
        else if (t < 240) { hzA[4000 + t] = 0u; hzB[4000 + t] = 0u; }  // rows 202..211
    }
    __syncthreads();

// conv1 via MFMA: wave wv owns m-tiles {wv, wv+4, wv+8} (+12 for wv==0).
// A-frag row = ml, k-slice = 4 contiguous u32 of xi. C layout: col=lane&15,
// row = q*4+r. mt==12 guard q<2 keeps m<200 (pad rows stay zero).
#define CONV1_NODE(nd, H1P) do {                                              \
    const int nTi = (wv == 0) ? 4 : 3;                                        \
    for (int ti = 0; ti < nTi; ++ti) {                                        \
        const int mt = wv + 4 * ti;                                           \
        unsigned int aw[4];                                                   \
        const int bi = mt * 16 + ml + 4 * q;                                  \
        aw[0] = xi[nd][bi];     aw[1] = xi[nd][bi + 1];                       \
        aw[2] = xi[nd][bi + 2]; aw[3] = xi[nd][bi + 3];                       \
        short8 af; __builtin_memcpy(&af, aw, 16);                             \
        float4v c0 = {0.f, 0.f, 0.f, 0.f};                                    \
        float4v c1 = {0.f, 0.f, 0.f, 0.f};                                    \
        c0 = __builtin_amdgcn_mfma_f32_16x16x32_bf16(af, w1f0, c0, 0, 0, 0);  \
        c1 = __builtin_amdgcn_mfma_f32_16x16x32_bf16(af, w1f1, c1, 0, 0, 0);  \
        if (mt < 12 || q < 2) {                                               \
            _Pragma("unroll")                                                 \
            for (int r = 0; r < 4; ++r) {                                     \
                const int m = mt * 16 + q * 4 + r;                            \
                *(unsigned int*)&H1P[(2 + m) * H1S + 2 * ml] =                \
                    pk2(fmaxf(c0[r] + b1lo, 0.f), fmaxf(c1[r] + b1hi, 0.f));  \
            }                                                                 \
        }                                                                     \
    }                                                                         \
} while (0)

#define CONV2_NODE(nd, H1P) do {                                              \
    float tA = 0.f, tB = 0.f;                                                 \
    const int mt0 = mh * 7, mtE = mh ? 13 : 7;                                \
    for (int mt = mt0; mt < mtE; ++mt) {                                      \
        float4v acc0 = {0.f, 0.f, 0.f, 0.f};                                  \
        float4v acc1 = {0.f, 0.f, 0.f, 0.f};                                  \
        _Pragma("unroll")                                                     \
        for (int kk = 0; kk < 5; ++kk) {                                      \
            const short8 a = *(const short8*)&H1P[(mt * 16 + ml + kk) * H1S + q * 8]; \
            acc0 = __builtin_amdgcn_mfma_f32_16x16x32_bf16(a, wfA[kk], acc0, 0, 0, 0); \
            acc1 = __builtin_amdgcn_mfma_f32_16x16x32_bf16(a, wfB[kk], acc1, 0, 0, 0); \
        }                                                                     \
        if (mt < 12) {                                                        \
            _Pragma("unroll")                                                 \
            for (int r = 0; r < 4; ++r) {                                     \
                tA += fmaxf(acc0[r] + bias2a, 0.f);                           \
                tB += fmaxf(acc1[r] + bias2b, 0.f);                           \
            }                                                                 \
        } else if (q < 2) {   /* m = 192 + q*4 + r < 200 */                   \
            _Pragma("unroll")                                                 \
            for (int r = 0; r < 4; ++r) {                                     \
                tA += fmaxf(acc0[r] + bias2a, 0.f);                           \
                tB += fmaxf(acc1[r] + bias2b, 0.f);                           \
            }                                                                 \
        }                                                                     \
    }                                                                         \
    tA += __shfl_xor(tA, 16, 64);                                             \
    tA += __shfl_xor(tA, 32, 64);                                             \
    tB += __shfl_xor(tB, 16, 64);                                             \
    tB += __shfl_xor(tB, 32, 64);                                             \
    tAn[nd] = tA;                                                             \
    tBn[nd] = tB;                                                             \
} while (0)

    float tAn[2], tBn[2];

    // conv1 node0 -> h1pA
    CONV1_NODE(0, h1pA);
    __syncthreads();

    // conv2(n0) from h1pA ; conv1(n1) into h1pB — independent buffers
    CONV2_NODE(0, h1pA);
    CONV1_NODE(1, h1pB);
    __syncthreads();

    // conv2 node1 from h1pB
    CONV2_NODE(1, h1pB);

#undef CONV1_NODE
#undef CONV2_NODE

    if (lane < 16) {
        red[wv][0][ml]      = tAn[0];   // oc = o2*32 + ml
        red[wv][0][16 + ml] = tBn[0];   // oc = o2*32 + 16 + ml
        red[wv][1][ml]      = tAn[1];
        red[wv][1][16 + ml] = tBn[1];
    }
    __syncthreads();
    if (t < 128) {
        const int nd = t >> 6, o = t & 63;
        const int grp = (o >> 5), idx = o & 31;   // waves grp, grp+2 hold this oc
        hm[nd][o] = (red[grp][nd][idx] + red[grp + 2][nd][idx]) * (1.0f / 200.0f);
    }
    __syncthreads();

    // fused Wh1 = hm @ W1 (f32); both nodes share the W1 column loads
    {
        const int o = t & 63, q4 = t >> 6;
        const float* Wp = W1 + (q4 * 16) * 64 + o;
        float p0 = 0.f, p1 = 0.f;
        #pragma unroll
        for (int k = 0; k < 16; ++k) {
            const float w = Wp[k * 64];
            p0 += hm[0][q4 * 16 + k] * w;
            p1 += hm[1][q4 * 16 + k] * w;
        }
        part[0][q4][o] = p0;
        part[1][q4][o] = p1;
    }
    __syncthreads();
    if (t < 128) {
        const int nd = t >> 6, o = t & 63;
        const int n = n0 + nd;
        const float v = part[nd][0][o] + part[nd][1][o] + part[nd][2][o] + part[nd][3][o];
        Wh_bt[((size_t)(b * 64 + o)) * 512 + n] = f2bf(v);
        float v1 = v * a1[o];
        float v2 = v * a1[64 + o];
        #pragma unroll
        for (int off = 32; off; off >>= 1) {
            v1 += __shfl_xor(v1, off, 64);
            v2 += __shfl_xor(v2, off, 64);
        }
        if (o == 0) { f1[b * 512 + n] = v1; f2[b * 512 + n] = v2; }
    }
}

// ---------------------------------------------------------------------------
// gat_attn_kernel: R5 structure (16-row i-tiles, 512 thr, 8 waves, accH
// K-split) + self-mask from adj + self-packed W2 B-frag (R9/R10-validated).
// ---------------------------------------------------------------------------
#define PSTR 520
__global__ __launch_bounds__(512) void gat_attn_kernel(
    const u16* __restrict__ Wh_bt,   // (8, 64, 512) bf16
    const float* __restrict__ f1in,
    const float* __restrict__ f2in,
    const int* __restrict__ adj,     // (512, 512)
    const float* __restrict__ W2g,   // (64, 64) GAT layer-2 W (fuse=1)
    const float* __restrict__ a2,    // (128,)       (fuse=1)
    u16* __restrict__ whbt_out,      // (8, 64, 512) (fuse=1)
    float* __restrict__ f1out,       //              (fuse=1)
    float* __restrict__ f2out,       //              (fuse=1)
    u16* __restrict__ outp,          // (4096, 64) bf16 (fuse=0)
    const int fuse)
{
    __shared__ __align__(16) u16 P[16 * PSTR];
    __shared__ float f2s[512];
    __shared__ float invs[16];
    __shared__ float f1s[16];
    __shared__ float accH[4][64][4];
    __shared__ __align__(16) u16 g1s[16 * 72];
    __shared__ __align__(16) u16 wh2s[64 * 20];
    __shared__ float fp1[4][16], fp2[4][16];

    const int t   = threadIdx.x;
    const int blk = blockIdx.x;
    const int b   = blk >> 5;
    const int i0  = (blk & 31) * 16;
    const int lane = t & 63, wv = t >> 6, nt = wv & 3, kh = wv >> 2;
    const int ml = lane & 15, q = lane >> 4;

    // prefetch B fragments for phase 2 (issue before softmax work)
    const u16* Bp = Wh_bt + ((size_t)(b * 64 + nt * 16 + ml)) * 512 + kh * 256 + q * 8;
    short8 bfr[8];
    #pragma unroll
    for (int ks = 0; ks < 8; ++ks)
        bfr[ks] = *(const short8*)(Bp + ks * 32);

    // adj row segment for phase-1 mask
    const int i_row = t >> 5, jseg0 = t & 31;
    const int4* ap = (const int4*)(adj + (size_t)(i0 + i_row) * 512 + jseg0 * 16);
    const int4 m0 = ap[0], m1 = ap[1], m2 = ap[2], m3 = ap[3];

    // W2 column floats for the fuse epilogue B-frag (packed later)
    float wgv[8];
    if (fuse) {
        #pragma unroll
        for (int j = 0; j < 8; ++j)
            wgv[j] = W2g[(kh * 32 + q * 8 + j) * 64 + nt * 16 + ml];
    }

    f2s[t & 511] = f2in[b * 512 + (t & 511)];
    if (t < 16) f1s[t] = f1in[b * 512 + i0 + t];
    __syncthreads();

    // phase 1: thread = (i_row, jseg0) -> 16 j's via in-register adj bits
    {
        const float f1i = f1s[i_row];
        unsigned int mbits = 0;
        mbits |= (m0.x > 0) ? 0x0001u : 0u;  mbits |= (m0.y > 0) ? 0x0002u : 0u;
        mbits |= (m0.z > 0) ? 0x0004u : 0u;  mbits |= (m0.w > 0) ? 0x0008u : 0u;
        mbits |= (m1.x > 0) ? 0x0010u : 0u;  mbits |= (m1.y > 0) ? 0x0020u : 0u;
        mbits |= (m1.z > 0) ? 0x0040u : 0u;  mbits |= (m1.w > 0) ? 0x0080u : 0u;
        mbits |= (m2.x > 0) ? 0x0100u : 0u;  mbits |= (m2.y > 0) ? 0x0200u : 0u;
        mbits |= (m2.z > 0) ? 0x0400u : 0u;  mbits |= (m2.w > 0) ? 0x0800u : 0u;
        mbits |= (m3.x > 0) ? 0x1000u : 0u;  mbits |= (m3.y > 0) ? 0x2000u : 0u;
        mbits |= (m3.z > 0) ? 0x4000u : 0u;  mbits |= (m3.w > 0) ? 0x8000u : 0u;
        const float* f2p = f2s + jseg0 * 16;
        float ev[16];
        float mx = -3.0e38f;
        #pragma unroll
        for (int v = 0; v < 16; ++v) {
            float e = f1i + f2p[v];
            e = e > 0.f ? e : 0.2f * e;
            e = ((mbits >> v) & 1u) ? e : NEGV;
            ev[v] = e;
            mx = fmaxf(mx, e);
        }
        mx = fmaxf(mx, __shfl_xor(mx, 1, 64));
        mx = fmaxf(mx, __shfl_xor(mx, 2, 64));
        mx = fmaxf(mx, __shfl_xor(mx, 4, 64));
        mx = fmaxf(mx, __shfl_xor(mx, 8, 64));
        mx = fmaxf(mx, __shfl_xor(mx, 16, 64));
        float sum = 0.f;
        #pragma unroll
        for (int v = 0; v < 16; ++v) {
            const float ex = __expf(ev[v] - mx);
            ev[v] = ex;
            sum += ex;
        }
        sum += __shfl_xor(sum, 1, 64);
        sum += __shfl_xor(sum, 2, 64);
        sum += __shfl_xor(sum, 4, 64);
        sum += __shfl_xor(sum, 8, 64);
        sum += __shfl_xor(sum, 16, 64);
        if (jseg0 == 0) invs[i_row] = 1.0f / sum;
        unsigned int* prow = (unsigned int*)&P[i_row * PSTR + jseg0 * 16];
        #pragma unroll
        for (int v = 0; v < 8; ++v)
            prow[v] = pk2(ev[2 * v], ev[2 * v + 1]);
    }
    __syncthreads();

    // phase 2: out(16x64) = P(16x512) @ Wh(512x64); wave = (nt, kh)
    float4v acc = {0.f, 0.f, 0.f, 0.f};
    #pragma unroll
    for (int ks = 0; ks < 8; ++ks) {
        const short8 afr = *(const short8*)&P[ml * PSTR + kh * 256 + ks * 32 + q * 8];
        acc = __builtin_amdgcn_mfma_f32_16x16x32_bf16(afr, bfr[ks], acc, 0, 0, 0);
    }
    if (kh == 1) {
        #pragma unroll
        for (int r = 0; r < 4; ++r) accH[nt][lane][r] = acc[r];
    }
    __syncthreads();
    if (kh == 0) {
        #pragma unroll
        for (int r = 0; r < 4; ++r) {
            const int i2 = q * 4 + r;
            float val = (acc[r] + accH[nt][lane][r]) * invs[i2];
            if (fuse) {
                val = fmaxf(val, 0.f);
                g1s[i2 * 72 + nt * 16 + ml] = f2bf(val);
            } else {
                outp[((size_t)(b * 512 + i0 + i2)) * 64 + nt * 16 + ml] = f2bf(val);
            }
        }
    }

    if (!fuse) return;

    // fused layer-2 Wh: Wh2(16x64) = g1s @ W2 ; wave = (nt, kh), 1 MFMA each
    __syncthreads();
    const short8 af2 = *(const short8*)&g1s[ml * 72 + kh * 32 + q * 8];
    short8 bf2v;
    {
        unsigned int wgp[4];
        #pragma unroll
        for (int d = 0; d < 4; ++d)
            wgp[d] = pk2(wgv[2 * d], wgv[2 * d + 1]);
        __builtin_memcpy(&bf2v, wgp, 16);
    }
    float4v c2 = {0.f, 0.f, 0.f, 0.f};
    c2 = __builtin_amdgcn_mfma_f32_16x16x32_bf16(af2, bf2v, c2, 0, 0, 0);
    if (kh == 1) {
        #pragma unroll
        for (int r = 0; r < 4; ++r) accH[nt][lane][r] = c2[r];
    }
    __syncthreads();
    if (kh == 0) {
        const int o = nt * 16 + ml;
        const float a2o1 = a2[o], a2o2 = a2[64 + o];
        #pragma unroll
        for (int r = 0; r < 4; ++r) {
            const float wv2 = c2[r] + accH[nt][lane][r];
            wh2s[o * 20 + q * 4 + r] = f2bf(wv2);
            float p1 = wv2 * a2o1, p2 = wv2 * a2o2;
            p1 += __shfl_xor(p1, 1, 64); p2 += __shfl_xor(p2, 1, 64);
            p1 += __shfl_xor(p1, 2, 64); p2 += __shfl_xor(p2, 2, 64);
            p1 += __shfl_xor(p1, 4, 64); p2 += __shfl_xor(p2, 4, 64);
            p1 += __shfl_xor(p1, 8, 64); p2 += __shfl_xor(p2, 8, 64);
            if (ml == 0) {
                fp1[nt][q * 4 + r] = p1;
                fp2[nt][q * 4 + r] = p2;
            }
        }
    }
    __syncthreads();
    if (t < 256) {
        const int o = t >> 2, seg = t & 3;
        *(uint2*)&whbt_out[((size_t)(b * 64 + o)) * 512 + i0 + seg * 4] =
            *(const uint2*)&wh2s[o * 20 + seg * 4];
    }
    if (t < 16) {
        f1out[b * 512 + i0 + t] = fp1[0][t] + fp1[1][t] + fp1[2][t] + fp1[3][t];
        f2out[b * 512 + i0 + t] = fp2[0][t] + fp2[1][t] + fp2[2][t] + fp2[3][t];
    }
}

// ---------------------------------------------------------------------------
// Kernel: edge MLP via MFMA, 16 edges/block. fc1 B-frags self-packed from
// fc1w (R9/R10-validated). hg is BF16 (pre-rounded in gat2): uint4 gather.
// ---------------------------------------------------------------------------
#define FSTR 136
__global__ __launch_bounds__(256) void edge_mlp_kernel(
    const u16* __restrict__ hg,         // (4096, 64) bf16
    const int* __restrict__ eidx,       // (2048, 2)
    const float* __restrict__ fc1w,     // (128, 64)
    const float* __restrict__ fc1b,     // (64,)
    const float* __restrict__ fc2w,     // (64, 1)
    const float* __restrict__ fc2b,     // (1,)
    float* __restrict__ out)            // (8, 2048)
{
    __shared__ __align__(16) u16 he[16 * FSTR];
    __shared__ float part[16][4];

    const int t   = threadIdx.x;
    const int blk = blockIdx.x;
    const int b   = blk >> 7;
    const int e0  = (blk & 127) * 16;
    const int lane = t & 63, wv = t >> 6, ml = lane & 15, q = lane >> 4;

    const int o = 16 * wv + ml;
    float fwv[32];
    #pragma unroll
    for (int ks = 0; ks < 4; ++ks) {
        #pragma unroll
        for (int j = 0; j < 8; ++j)
            fwv[ks * 8 + j] = fc1w[(ks * 32 + q * 8 + j) * 64 + o];
    }
    const float bo = fc1b[o];
    const float wo = fc2w[o];

    {
        const int ep = t >> 4, p = t & 15;
        const int e = e0 + ep;
        const int node = (p < 8) ? eidx[e * 2] : eidx[e * 2 + 1];
        const int c0 = (p & 7) * 8;
        const u16* hp = hg + ((size_t)(b * 512 + node)) * 64 + c0;
        *(uint4v*)&he[ep * FSTR + ((p < 8) ? 0 : 64) + c0] = *(const uint4v*)hp;
    }
    __syncthreads();

    short8 bw[4];
    #pragma unroll
    for (int ks = 0; ks < 4; ++ks) {
        unsigned int wp[4];
        #pragma unroll
        for (int d = 0; d < 4; ++d)
            wp[d] = pk2(fwv[ks * 8 + 2 * d], fwv[ks * 8 + 2 * d + 1]);
        __builtin_memcpy(&bw[ks], wp, 16);
    }

    float4v acc = {0.f, 0.f, 0.f, 0.f};
    #pragma unroll
    for (int ks = 0; ks < 4; ++ks) {
        const short8 afr = *(const short8*)&he[ml * FSTR + ks * 32 + q * 8];
        acc = __builtin_amdgcn_mfma_f32_16x16x32_bf16(afr, bw[ks], acc, 0, 0, 0);
    }
    #pragma unroll
    for (int r = 0; r < 4; ++r) {
        float z = fmaxf(acc[r] + bo, 0.f) * wo;
        z += __shfl_xor(z, 1, 64);
        z += __shfl_xor(z, 2, 64);
        z += __shfl_xor(z, 4, 64);
        z += __shfl_xor(z, 8, 64);
        if (ml == 0) part[q * 4 + r][wv] = z;
    }
    __syncthreads();
    if (t < 16) {
        const float v = part[t][0] + part[t][1] + part[t][2] + part[t][3] + fc2b[0];
        out[b * 2048 + e0 + t] = 1.0f / (1.0f + __expf(-v));
    }
}

// ---------------------------------------------------------------------------
extern "C" void kernel_launch(void* const* d_in, const int* in_sizes, int n_in,
                              void* d_out, int out_size, void* d_ws, size_t ws_size,
                              hipStream_t stream) {
    const float* x    = (const float*)d_in[0];
    const int* adj    = (const int*)d_in[1];
    const int* eidx   = (const int*)d_in[2];
    const float* w1   = (const float*)d_in[3];
    const float* b1   = (const float*)d_in[4];
    const float* w2   = (const float*)d_in[5];
    const float* b2   = (const float*)d_in[6];
    const float* W1   = (const float*)d_in[7];
    const float* a1   = (const float*)d_in[8];
    const float* W2   = (const float*)d_in[9];
    const float* a2   = (const float*)d_in[10];
    const float* fc1w = (const float*)d_in[11];
    const float* fc1b = (const float*)d_in[12];
    const float* fc2w = (const float*)d_in[13];
    const float* fc2b = (const float*)d_in[14];
    float* out = (float*)d_out;

    float* ws = (float*)d_ws;
    const size_t R = (size_t)BATCH * NNODE;       // 4096
    float* f1a   = ws;                            // R
    float* f2a   = f1a + R;                       // R
    float* f1b   = f2a + R;                       // R
    float* f2b   = f1b + R;                       // R
    u16*   g_bt  = (u16*)(f2b + R);               // R*64 bf16 (layer-2 out)
    u16*   whbt1 = g_bt + R * 64;                 // R*64
    u16*   whbt2 = whbt1 + R * 64;                // R*64
    u16*   w2f   = whbt2 + R * 64;                // 10240

    pre_kernel<<<dim3(4), dim3(256), 0, stream>>>(w2, w2f);
    conv_fused_kernel<<<dim3(2048), dim3(256), 0, stream>>>(
        x, w1, b1, b2, W1, a1, w2f, whbt1, f1a, f2a);
    gat_attn_kernel<<<dim3(256), dim3(512), 0, stream>>>(
        whbt1, f1a, f2a, adj, W2, a2, whbt2, f1b, f2b, g_bt, 1);
    gat_attn_kernel<<<dim3(256), dim3(512), 0, stream>>>(
        whbt2, f1b, f2b, adj, W2, a2, whbt2, f1b, f2b, g_bt, 0);
    edge_mlp_kernel<<<dim3(1024), dim3(256), 0, stream>>>(
        g_bt, eidx, fc1w, fc1b, fc2w, fc2b, out);
}